// Round 1
// baseline (597.703 us; speedup 1.0000x reference)
//
#include <hip/hip_runtime.h>
#include <hip/hip_bf16.h>

#define SEQ 512
#define BATCH 256
#define IN_DIM 150
#define HID 4

#if __has_builtin(__builtin_amdgcn_exp2f)
__device__ __forceinline__ float fexp2(float x){ return __builtin_amdgcn_exp2f(x); }
#else
__device__ __forceinline__ float fexp2(float x){ return exp2f(x); }
#endif
#if __has_builtin(__builtin_amdgcn_rcpf)
__device__ __forceinline__ float frcp(float x){ return __builtin_amdgcn_rcpf(x); }
#else
__device__ __forceinline__ float frcp(float x){ return 1.0f/(x); }
#endif

__device__ __forceinline__ float sigm(float x){ return frcp(1.0f + fexp2(-1.44269504088896341f*x)); }
__device__ __forceinline__ float tanhx(float x){ return 1.0f - 2.0f*frcp(1.0f + fexp2(2.88539008177792681f*x)); }

// DPP quad_perm cross-lane move: CTRL encodes the 4-lane permutation.
template<int CTRL>
__device__ __forceinline__ float dppq(float v){
    return __int_as_float(__builtin_amdgcn_mov_dpp(__float_as_int(v), CTRL, 0xF, 0xF, true));
}

// ---------------------------------------------------------------------------
// Kernel 1: layer-0 input projection.
// xp[r*16 + k*4 + j] = dot(x[r,:], w_ih0[j*4+k,:]) + b_ih0[j*4+k] + b_hh0[j*4+k]
// (k = hidden unit 0..3, j = gate class i/f/g/o) -> scan reads one float4/thread.
// ---------------------------------------------------------------------------
__global__ __launch_bounds__(256) void xproj(const float* __restrict__ x,
                                             const float* __restrict__ w,
                                             const float* __restrict__ bih,
                                             const float* __restrict__ bhh,
                                             float* __restrict__ xp)
{
    const int r = blockIdx.x*256 + threadIdx.x;
    const float* xr = x + (size_t)r*IN_DIM;
    float acc[16];
#pragma unroll
    for (int g=0; g<16; ++g) acc[g] = bih[g] + bhh[g];
#pragma unroll 3
    for (int dq=0; dq<IN_DIM/2; ++dq) {
        const float2 xv = *(const float2*)(xr + dq*2);
#pragma unroll
        for (int g=0; g<16; ++g) {
            // w pointer arithmetic is thread-uniform -> scalar (SGPR) loads
            const float2 wv = *(const float2*)(w + g*IN_DIM + dq*2);
            acc[g] += xv.x*wv.x + xv.y*wv.y;
        }
    }
    float4* op = (float4*)(xp + (size_t)r*16);
#pragma unroll
    for (int k=0;k<4;++k)
        op[k] = make_float4(acc[k], acc[4+k], acc[8+k], acc[12+k]);
}

// ---------------------------------------------------------------------------
// Kernel 2: recurrent scan for one layer. 4 threads per batch element (one per
// hidden unit). No barriers: batch elements independent; intra-quad h exchange
// via DPP. MODE 0: layer0 (reads precomputed xp). MODE 1: mid layer (reads
// prev-layer h, folds 16x4 input proj). MODE 2: last layer + fused FC head.
// ---------------------------------------------------------------------------
template<int MODE>
__global__ __launch_bounds__(64) void lstm_scan(
    const float* __restrict__ xin,
    const float* __restrict__ wih,
    const float* __restrict__ whh,
    const float* __restrict__ bih,
    const float* __restrict__ bhh,
    const float* __restrict__ fcw,
    const float* __restrict__ fcb,
    float* __restrict__ out)
{
    const int lane = threadIdx.x;
    const int k = lane & 3;           // hidden unit
    const int b = blockIdx.x*16 + (lane>>2);

    // Per-thread weights. whp is xor-permuted so shuffled h values (a_m = h_{k^m})
    // can be consumed with static indices (avoids runtime-indexed arrays -> scratch).
    float whp[4][4], wir[4][4], bias[4], fcp[4];
    float fcbv = 0.f;
#pragma unroll
    for (int j=0;j<4;++j) {
        const int row = j*4+k;        // gate row in (16, .) weight
#pragma unroll
        for (int m=0;m<4;++m) whp[j][m] = whh[row*4 + (k^m)];
        if (MODE != 0) {
#pragma unroll
            for (int m=0;m<4;++m) wir[j][m] = wih[row*4 + m];
            bias[j] = bih[row] + bhh[row];
        } else {
            bias[j] = 0.f;
#pragma unroll
            for (int m=0;m<4;++m) wir[j][m] = 0.f;
        }
    }
    if (MODE == 2) {
#pragma unroll
        for (int m=0;m<4;++m) fcp[m] = fcw[k^m];
        fcbv = fcb[0];
    }

    const float* base;
    int stride;
    if (MODE==0) { base = xin + (size_t)b*16 + k*4; stride = BATCH*16; }
    else         { base = xin + (size_t)b*4;        stride = BATCH*4;  }

    float h=0.f, c=0.f, a0=0.f, a1=0.f, a2=0.f, a3=0.f;

    auto LD = [&](int t)->float4 {
        const int tcl = t > SEQ-1 ? SEQ-1 : t;   // clamp (uniform) for over-prefetch
        return *(const float4*)(base + (size_t)tcl*stride);
    };

    auto STEP = [&](float4 xv, int t) {
        float g0,g1,g2,g3;
        if (MODE==0) { g0=xv.x; g1=xv.y; g2=xv.z; g3=xv.w; }
        else {
            g0 = bias[0] + wir[0][0]*xv.x + wir[0][1]*xv.y + wir[0][2]*xv.z + wir[0][3]*xv.w;
            g1 = bias[1] + wir[1][0]*xv.x + wir[1][1]*xv.y + wir[1][2]*xv.z + wir[1][3]*xv.w;
            g2 = bias[2] + wir[2][0]*xv.x + wir[2][1]*xv.y + wir[2][2]*xv.z + wir[2][3]*xv.w;
            g3 = bias[3] + wir[3][0]*xv.x + wir[3][1]*xv.y + wir[3][2]*xv.z + wir[3][3]*xv.w;
        }
        g0 += whp[0][0]*a0 + whp[0][1]*a1 + whp[0][2]*a2 + whp[0][3]*a3;
        g1 += whp[1][0]*a0 + whp[1][1]*a1 + whp[1][2]*a2 + whp[1][3]*a3;
        g2 += whp[2][0]*a0 + whp[2][1]*a1 + whp[2][2]*a2 + whp[2][3]*a3;
        g3 += whp[3][0]*a0 + whp[3][1]*a1 + whp[3][2]*a2 + whp[3][3]*a3;
        const float ig = sigm(g0);
        const float fg = sigm(g1);
        const float gg = tanhx(g2);
        const float og = sigm(g3);
        c = fg*c + ig*gg;
        h = og * tanhx(c);
        a0 = h;
        a1 = dppq<0xB1>(h);   // h from lane k^1
        a2 = dppq<0x4E>(h);   // h from lane k^2
        a3 = dppq<0x1B>(h);   // h from lane k^3
        if (MODE==2) {
            const float ov = fcbv + fcp[0]*a0 + fcp[1]*a1 + fcp[2]*a2 + fcp[3]*a3;
            if (k==0) out[(size_t)t*BATCH + b] = ov;
        } else {
            out[((size_t)t*BATCH + b)*4 + k] = h;
        }
    };

    // software-pipelined: prefetch 4..8 steps ahead in named double buffers
    float4 A0=LD(0), A1=LD(1), A2=LD(2), A3=LD(3);
    for (int t=0; t<SEQ; t+=8) {
        float4 B0=LD(t+4), B1=LD(t+5), B2=LD(t+6), B3=LD(t+7);
        STEP(A0,t);   STEP(A1,t+1); STEP(A2,t+2); STEP(A3,t+3);
        A0=LD(t+8); A1=LD(t+9); A2=LD(t+10); A3=LD(t+11);
        STEP(B0,t+4); STEP(B1,t+5); STEP(B2,t+6); STEP(B3,t+7);
    }
}

// ---------------------------------------------------------------------------
extern "C" void kernel_launch(void* const* d_in, const int* in_sizes, int n_in,
                              void* d_out, int out_size, void* d_ws, size_t ws_size,
                              hipStream_t stream)
{
    const float* x      = (const float*)d_in[0];
    const float* w_ih0  = (const float*)d_in[1];
    const float* w_hh0  = (const float*)d_in[2];
    const float* b_ih0  = (const float*)d_in[3];
    const float* b_hh0  = (const float*)d_in[4];
    const float* w_ih_r = (const float*)d_in[5];   // (3,16,4)
    const float* w_hh_r = (const float*)d_in[6];   // (3,16,4)
    const float* b_ih_r = (const float*)d_in[7];   // (3,16)
    const float* b_hh_r = (const float*)d_in[8];   // (3,16)
    const float* fc_w   = (const float*)d_in[9];   // (1,4)
    const float* fc_b   = (const float*)d_in[10];  // (1,)
    float* out = (float*)d_out;

    float* xp0 = (float*)d_ws;                          // SEQ*BATCH*16 f32 = 8 MB
    float* hA  = xp0 + (size_t)SEQ*BATCH*16;            // SEQ*BATCH*4  f32 = 2 MB
    float* hB  = hA  + (size_t)SEQ*BATCH*4;             // 2 MB

    xproj<<<SEQ*BATCH/256, 256, 0, stream>>>(x, w_ih0, b_ih0, b_hh0, xp0);
    lstm_scan<0><<<16,64,0,stream>>>(xp0, nullptr,    w_hh0,     nullptr,    nullptr,    nullptr, nullptr, hA);
    lstm_scan<1><<<16,64,0,stream>>>(hA,  w_ih_r,     w_hh_r,    b_ih_r,     b_hh_r,     nullptr, nullptr, hB);
    lstm_scan<1><<<16,64,0,stream>>>(hB,  w_ih_r+64,  w_hh_r+64, b_ih_r+16,  b_hh_r+16,  nullptr, nullptr, hA);
    lstm_scan<2><<<16,64,0,stream>>>(hA,  w_ih_r+128, w_hh_r+128,b_ih_r+32,  b_hh_r+32,  fc_w,    fc_b,    out);
}

// Round 3
// 270.131 us; speedup vs baseline: 2.2126x; 2.2126x over previous
//
#include <hip/hip_runtime.h>
#include <hip/hip_bf16.h>

#define SEQ 512
#define BATCH 256
#define IN_DIM 150

#if __has_builtin(__builtin_amdgcn_exp2f)
__device__ __forceinline__ float fexp2(float x){ return __builtin_amdgcn_exp2f(x); }
#else
__device__ __forceinline__ float fexp2(float x){ return exp2f(x); }
#endif
#if __has_builtin(__builtin_amdgcn_rcpf)
__device__ __forceinline__ float frcp(float x){ return __builtin_amdgcn_rcpf(x); }
#else
__device__ __forceinline__ float frcp(float x){ return 1.0f/(x); }
#endif

__device__ __forceinline__ float sigm(float x){ return frcp(1.0f + fexp2(-1.44269504088896341f*x)); }
__device__ __forceinline__ float tanhx(float x){ return 1.0f - 2.0f*frcp(1.0f + fexp2(2.88539008177792681f*x)); }

// DPP cross-lane move. quad_perm: 0xB1 = xor1, 0x4E = xor2, 0x1B = xor3.
// 0x114 = row_shr:4 (lane i <- lane i-4 within 16-lane row; bound lanes -> 0).
template<int CTRL>
__device__ __forceinline__ float dppmov(float v){
    return __int_as_float(__builtin_amdgcn_mov_dpp(__float_as_int(v), CTRL, 0xF, 0xF, true));
}

// ---------------------------------------------------------------------------
// Kernel 1: layer-0 input projection, weights staged in LDS (broadcast reads).
// xp[r*16 + k*4 + j] = dot(x[r,:], w_ih0[j*4+k,:]) + b_ih0[.] + b_hh0[.]
// ---------------------------------------------------------------------------
__global__ __launch_bounds__(256) void xproj(const float* __restrict__ x,
                                             const float* __restrict__ w,
                                             const float* __restrict__ bih,
                                             const float* __restrict__ bhh,
                                             float* __restrict__ xp)
{
    __shared__ float wl[16*IN_DIM];
    __shared__ float bl[16];
    for (int i=threadIdx.x; i<16*IN_DIM; i+=256) wl[i] = w[i];
    if (threadIdx.x < 16) bl[threadIdx.x] = bih[threadIdx.x] + bhh[threadIdx.x];
    __syncthreads();

    const int r = blockIdx.x*256 + threadIdx.x;
    const float* xr = x + (size_t)r*IN_DIM;
    float acc[16];
#pragma unroll
    for (int g=0; g<16; ++g) acc[g] = bl[g];
#pragma unroll 5
    for (int dq=0; dq<IN_DIM/2; ++dq) {
        const float2 xv = *(const float2*)(xr + dq*2);
#pragma unroll
        for (int g=0; g<16; ++g) {
            const float2 wv = *(const float2*)(&wl[g*IN_DIM + dq*2]); // broadcast, conflict-free
            acc[g] += xv.x*wv.x + xv.y*wv.y;
        }
    }
    float4* op = (float4*)(xp + (size_t)r*16);
#pragma unroll
    for (int kk=0; kk<4; ++kk)
        op[kk] = make_float4(acc[kk], acc[4+kk], acc[8+kk], acc[12+kk]);
}

// ---------------------------------------------------------------------------
// Kernel 2: all 4 layers wavefront-pipelined in one wave.
// lane = bb*16 + l*4 + k  (bb: batch elem in wave, l: layer, k: hidden unit)
// Layer l computes step t = tau - l at super-step tau. Handoff l-1 -> l via
// row_shr:4 DPP; own-layer h exchange via quad_perm DPP. All weights are
// xor-permuted per-lane so shuffled values use static indexing.
// ---------------------------------------------------------------------------
__global__ __launch_bounds__(64) void lstm_pipe(
    const float* __restrict__ xp,
    const float* __restrict__ w_hh0,
    const float* __restrict__ w_ih_r,
    const float* __restrict__ w_hh_r,
    const float* __restrict__ b_ih_r,
    const float* __restrict__ b_hh_r,
    const float* __restrict__ fcw,
    const float* __restrict__ fcb,
    float* __restrict__ out)
{
    const int lane = threadIdx.x;
    const int k  = lane & 3;
    const int l  = (lane >> 2) & 3;
    const int bb = lane >> 4;
    const int b  = blockIdx.x*4 + bb;

    // Per-lane weights (xor-permuted in m so shuffled a_m = h_{k^m} consume
    // with static indices). Layer 0 uses identity wir (input already projected).
    const float* whh = (l==0) ? w_hh0 : (w_hh_r + (size_t)(l-1)*64);
    float whp[4][4], wir[4][4], bias[4], fcp[4];
#pragma unroll
    for (int j=0;j<4;++j) {
        const int row = j*4+k;
#pragma unroll
        for (int m=0;m<4;++m) whp[j][m] = whh[row*4 + (k^m)];
        if (l==0) {
            bias[j] = 0.f;
#pragma unroll
            for (int m=0;m<4;++m) wir[j][m] = (m==j) ? 1.f : 0.f;
        } else {
            const float* wih = w_ih_r + (size_t)(l-1)*64;
            bias[j] = b_ih_r[(l-1)*16+row] + b_hh_r[(l-1)*16+row];
#pragma unroll
            for (int m=0;m<4;++m) wir[j][m] = wih[row*4 + (k^m)];
        }
    }
#pragma unroll
    for (int m=0;m<4;++m) fcp[m] = fcw[k^m];
    const float fcbv = fcb[0];

    // All 16 lanes of a batch element read the same 64B xp line -> coalesces.
    const float* xbase = xp + (size_t)b*16 + k*4;

    float h=0.f, c=0.f;
    float a0=0.f,a1=0.f,a2=0.f,a3=0.f;   // own-layer inputs (xor-permuted h)
    float s0=0.f,s1=0.f,s2=0.f,s3=0.f;   // prev-layer inputs (row-shifted)

    auto LDX = [&](int t)->float4 {
        const int tc = t < SEQ-1 ? t : SEQ-1;
        return *(const float4*)(xbase + (size_t)tc*(BATCH*16));
    };

    auto STEP = [&](float4 xv, int tau) {
        const float x0 = (l==0) ? xv.x : s0;
        const float x1 = (l==0) ? xv.y : s1;
        const float x2 = (l==0) ? xv.z : s2;
        const float x3 = (l==0) ? xv.w : s3;
        // tree-shaped dot-8 to shorten the dependent chain
        float g0 = (bias[0] + ((wir[0][0]*x0 + wir[0][1]*x1) + (wir[0][2]*x2 + wir[0][3]*x3)))
                 + ((whp[0][0]*a0 + whp[0][1]*a1) + (whp[0][2]*a2 + whp[0][3]*a3));
        float g1 = (bias[1] + ((wir[1][0]*x0 + wir[1][1]*x1) + (wir[1][2]*x2 + wir[1][3]*x3)))
                 + ((whp[1][0]*a0 + whp[1][1]*a1) + (whp[1][2]*a2 + whp[1][3]*a3));
        float g2 = (bias[2] + ((wir[2][0]*x0 + wir[2][1]*x1) + (wir[2][2]*x2 + wir[2][3]*x3)))
                 + ((whp[2][0]*a0 + whp[2][1]*a1) + (whp[2][2]*a2 + whp[2][3]*a3));
        float g3 = (bias[3] + ((wir[3][0]*x0 + wir[3][1]*x1) + (wir[3][2]*x2 + wir[3][3]*x3)))
                 + ((whp[3][0]*a0 + whp[3][1]*a1) + (whp[3][2]*a2 + whp[3][3]*a3));
        const float ig = sigm(g0);
        const float fg = sigm(g1);
        const float gg = tanhx(g2);
        const float og = sigm(g3);
        c = fg*c + ig*gg;
        h = og * tanhx(c);
        const int t = tau - l;
        if (t < 0) { h = 0.f; c = 0.f; }     // warm-up: state must be 0 entering t=0
        a0 = h;
        a1 = dppmov<0xB1>(h);
        a2 = dppmov<0x4E>(h);
        a3 = dppmov<0x1B>(h);
        s0 = dppmov<0x114>(a0);              // hand layer l's h down to layer l+1
        s1 = dppmov<0x114>(a1);
        s2 = dppmov<0x114>(a2);
        s3 = dppmov<0x114>(a3);
        if (l==3 && k==0 && t >= 0 && t < SEQ) {
            out[(size_t)t*BATCH + b] =
                fcbv + ((fcp[0]*a0 + fcp[1]*a1) + (fcp[2]*a2 + fcp[3]*a3));
        }
    };

    // 515 needed super-steps, rounded to 520 (65 x 8); extras are masked/clamped.
    float4 A0=LDX(0), A1=LDX(1), A2=LDX(2), A3=LDX(3);
    for (int tau=0; tau<520; tau+=8) {
        float4 B0=LDX(tau+4), B1=LDX(tau+5), B2=LDX(tau+6), B3=LDX(tau+7);
        STEP(A0,tau);   STEP(A1,tau+1); STEP(A2,tau+2); STEP(A3,tau+3);
        A0=LDX(tau+8);  A1=LDX(tau+9);  A2=LDX(tau+10); A3=LDX(tau+11);
        STEP(B0,tau+4); STEP(B1,tau+5); STEP(B2,tau+6); STEP(B3,tau+7);
    }
}

// ---------------------------------------------------------------------------
extern "C" void kernel_launch(void* const* d_in, const int* in_sizes, int n_in,
                              void* d_out, int out_size, void* d_ws, size_t ws_size,
                              hipStream_t stream)
{
    const float* x      = (const float*)d_in[0];
    const float* w_ih0  = (const float*)d_in[1];
    const float* w_hh0  = (const float*)d_in[2];
    const float* b_ih0  = (const float*)d_in[3];
    const float* b_hh0  = (const float*)d_in[4];
    const float* w_ih_r = (const float*)d_in[5];   // (3,16,4)
    const float* w_hh_r = (const float*)d_in[6];   // (3,16,4)
    const float* b_ih_r = (const float*)d_in[7];   // (3,16)
    const float* b_hh_r = (const float*)d_in[8];   // (3,16)
    const float* fc_w   = (const float*)d_in[9];   // (1,4)
    const float* fc_b   = (const float*)d_in[10];  // (1,)
    float* out = (float*)d_out;

    float* xp0 = (float*)d_ws;                     // SEQ*BATCH*16 f32 = 8 MB

    xproj<<<SEQ*BATCH/256, 256, 0, stream>>>(x, w_ih0, b_ih0, b_hh0, xp0);
    lstm_pipe<<<BATCH/4, 64, 0, stream>>>(xp0, w_hh0, w_ih_r, w_hh_r,
                                          b_ih_r, b_hh_r, fc_w, fc_b, out);
}